// Round 4
// baseline (99.133 us; speedup 1.0000x reference)
//
#include <hip/hip_runtime.h>

// SKA involution-style conv:
// out[b, i*32+g, h, w] = sum_{di,dj} x[b, i*32+g, h+di-1, w+dj-1] * w[b, g, 3*di+dj, h, w]
// x: (8,256,56,56) f32, w: (8,32,9,56,56) f32, out: (8,256,56,56) f32
//
// R4 = R3 (LDS-tiled, traffic-minimal) + w-prefetch before the staging barrier:
// the 9 per-pixel weight float4s are independent of the LDS staging, so issue
// them at kernel start and let staging + barrier cover their latency.

#define HW 3136
#define W_DIM 56
#define LDS_STRIDE 60   // floats per LDS row; 60*4=240 B keeps row bases 16B-aligned
#define BAND 14
#define XROWS 16        // BAND + 2 halo rows

__global__ __launch_bounds__(256) void SKA_20950850470021_kernel(
    const float* __restrict__ x, const float* __restrict__ wt,
    float* __restrict__ out) {
  __shared__ float lx[8 * XROWS * LDS_STRIDE];   // 30720 B

  const int pg   = blockIdx.x;    // b*32 + g
  const int band = blockIdx.y;    // 0..3
  const int h0   = band * BAND;
  const int b    = pg >> 5;
  const int g    = pg & 31;
  const int tid  = threadIdx.x;

  // --- compute-thread coords + w prefetch (issued BEFORE staging/barrier) ---
  const bool is_comp = tid < BAND * 14;
  const int q  = tid % 14;
  const int r  = tid / 14;        // valid only when is_comp
  const int gr = h0 + r;
  const int c0 = 4 * q;

  float4 wk[9];
  if (is_comp) {
    const float* wb = wt + (size_t)pg * 9 * HW + gr * W_DIM + c0;
#pragma unroll
    for (int k = 0; k < 9; ++k) wk[k] = *(const float4*)(wb + (size_t)k * HW);
  }

  // --- zero halo columns (LDS col 0 and 57) for every (ch,row): 256 cells ---
  {
    const int ch  = tid >> 5;
    const int rr  = (tid >> 1) & 15;
    const int col = (tid & 1) ? 57 : 0;
    lx[(ch * XROWS + rr) * LDS_STRIDE + col] = 0.f;
  }

  // --- stage x rows h0-1 .. h0+14 into LDS cols 1..56 (zeros out-of-plane) ---
  // 8 ch x 16 rows x 14 float4 = 1792 units = 256 threads x 7 iters.
  const float* xg = x + ((size_t)b * 256 + g) * HW;
#pragma unroll
  for (int it = 0; it < 7; ++it) {
    const int idx = tid + it * 256;     // 0..1791
    const int j   = idx % 14;           // col quad
    const int u   = idx / 14;           // (ch, row)
    const int ch  = u >> 4;
    const int rr  = u & 15;
    const int grr = h0 + rr - 1;
    float4 v = make_float4(0.f, 0.f, 0.f, 0.f);
    if ((unsigned)grr < 56u)
      v = *(const float4*)(xg + (size_t)ch * 32 * HW + grr * W_DIM + 4 * j);
    float* d = &lx[(ch * XROWS + rr) * LDS_STRIDE + 1 + 4 * j];
    d[0] = v.x; d[1] = v.y; d[2] = v.z; d[3] = v.w;
  }

  __syncthreads();

  if (!is_comp) return;

  float* ob = out + ((size_t)b * 256 + g) * HW + gr * W_DIM + c0;

#pragma unroll
  for (int ch = 0; ch < 8; ++ch) {
    // x rows gr-1..gr+1 = LDS rows r..r+2; x cols c0-1..c0+4 = LDS cols 4q..4q+5
    float xr[3][6];
#pragma unroll
    for (int dr = 0; dr < 3; ++dr) {
      const float* p = &lx[(ch * XROWS + r + dr) * LDS_STRIDE + 4 * q];
      const float4 a  = *(const float4*)p;
      const float2 bb = *(const float2*)(p + 4);
      xr[dr][0] = a.x; xr[dr][1] = a.y; xr[dr][2] = a.z; xr[dr][3] = a.w;
      xr[dr][4] = bb.x; xr[dr][5] = bb.y;
    }

    float4 acc = make_float4(0.f, 0.f, 0.f, 0.f);
#pragma unroll
    for (int di = 0; di < 3; ++di)
#pragma unroll
      for (int dj = 0; dj < 3; ++dj) {
        const float4 W = wk[di * 3 + dj];
        acc.x = fmaf(xr[di][dj + 0], W.x, acc.x);
        acc.y = fmaf(xr[di][dj + 1], W.y, acc.y);
        acc.z = fmaf(xr[di][dj + 2], W.z, acc.z);
        acc.w = fmaf(xr[di][dj + 3], W.w, acc.w);
      }
    *(float4*)(ob + (size_t)ch * 32 * HW) = acc;
  }
}

extern "C" void kernel_launch(void* const* d_in, const int* in_sizes, int n_in,
                              void* d_out, int out_size, void* d_ws, size_t ws_size,
                              hipStream_t stream) {
  const float* x  = (const float*)d_in[0];
  const float* wt = (const float*)d_in[1];
  float* out = (float*)d_out;

  dim3 grid(256, 4);   // (b*32+g) x row-band
  SKA_20950850470021_kernel<<<grid, 256, 0, stream>>>(x, wt, out);
}